// Round 2
// baseline (269.234 us; speedup 1.0000x reference)
//
#include <hip/hip_runtime.h>
#include <hip/hip_bf16.h>

#define N_NODES 20000
#define MPAD    20096
#define E_EDGES 400000
#define LATENT 128
#define H1 256
#define HIDDEN 512
#define OUT_D 64
#define HEADS 4
#define NEG_SLOPE 0.2f
// max in-degree slots: deg ~ Binomial(400k, 1/20k), mean 20, sigma 4.47; 66 edges = ~10.3 sigma
#define MAX_IN 67

typedef __attribute__((ext_vector_type(8))) __bf16 bf16x8;
typedef __attribute__((ext_vector_type(4))) float f32x4;
typedef __attribute__((ext_vector_type(4))) unsigned short u16x4;

__device__ __forceinline__ unsigned short f2bf(float f) {
    union { float f; unsigned int u; } v; v.f = f;
    unsigned int r = v.u + 0x7fffu + ((v.u >> 16) & 1u);  // RNE
    return (unsigned short)(r >> 16);
}
__device__ __forceinline__ float bf2f(unsigned short u) {
    union { unsigned int u; float f; } v; v.u = ((unsigned int)u) << 16;
    return v.f;
}

// ---------------- weights transpose-convert (R17: histogram removed — cur[] after scatter IS deg) ----
#define SEG1 (LATENT * H1)
#define SEG2 (H1 * HIDDEN)
#define SEG3 (HIDDEN * HEADS * OUT_D)
#define WTOT (SEG1 + SEG2 + SEG3)
__global__ __launch_bounds__(256)
void prep_kernel(const float* __restrict__ W1, const float* __restrict__ W2,
                 const float* __restrict__ Wg,
                 unsigned short* __restrict__ W1t, unsigned short* __restrict__ W2t,
                 unsigned short* __restrict__ Wgt) {
    int t = blockIdx.x * blockDim.x + threadIdx.x;
    if (t < SEG1) { int k = t >> 8, n = t & 255; W1t[n * LATENT + k] = f2bf(W1[t]); return; }
    t -= SEG1;
    if (t < SEG2) { int k = t >> 9, n = t & 511; W2t[n * H1 + k] = f2bf(W2[t]); return; }
    t -= SEG2;
    if (t < SEG3) { int k = t >> 8, n = t & 255; Wgt[n * HIDDEN + k] = f2bf(Wg[t]); }
}

// ---------------- fully fused MLP + att coefs (R15 config — best measured; UNCHANGED) ----------------
// TM=32, 628 blocks, 256 threads; 50 KB LDS -> 3 blocks/CU -> whole grid co-resident;
// duration == one block's latency chain (~58 us). Known floor from prior session.
#define TM 32
#define ZPITCH 136
#define XPITCH 264
#define X2PITCH 520
__global__ __launch_bounds__(256, 4)
void mlp_all_kernel(const float* __restrict__ z,
                    const unsigned short* __restrict__ W1t,
                    const unsigned short* __restrict__ W2t,
                    const unsigned short* __restrict__ Wgt,
                    const float* __restrict__ b1, const float* __restrict__ b2,
                    const float* __restrict__ att_src, const float* __restrict__ att_dst,
                    unsigned short* __restrict__ hb,
                    float* __restrict__ a_src, float* __restrict__ a_dst) {
    __shared__ unsigned short x2s[TM * X2PITCH];   // 33.3 KB; first 8.7 KB aliased as zbf
    __shared__ unsigned short x1s[TM * XPITCH];    // 16.9 KB (50.2 KB total)
    unsigned short* zbf = x2s;
    const int tid = threadIdx.x;
    const int wave = tid >> 6, lane = tid & 63;
    const int m0 = blockIdx.x * TM;
    const int fr = lane & 15, q = lane >> 4;

#define LDW1(kt, t)      (*(const bf16x8*)(W1t + (size_t)(nb1 + (t) * 16 + fr) * LATENT + (kt) * 32 + q * 8))
#define LDW2H(nh, kt, t) (*(const bf16x8*)(W2t + (size_t)(nb2 + (nh) * 64 + (t) * 16 + fr) * H1 + (kt) * 32 + q * 8))
#define LDW3(kt, t)      (*(const bf16x8*)(Wgt + (size_t)(nb3 + (t) * 16 + fr) * HIDDEN + (kt) * 32 + q * 8))

    const int nb1 = wave * 64;
    const int nb2 = wave * 128;
    const int head = wave;
    const int nb3 = wave * 64;

    bf16x8 w1a[4], w1b[4];
#pragma unroll
    for (int t = 0; t < 4; t++) w1a[t] = LDW1(0, t);

    {
        const int r = tid >> 3, c0 = (tid & 7) * 16;
        const int zrow = min(m0 + r, N_NODES - 1);
        const float* zp = z + (size_t)zrow * LATENT + c0;
#pragma unroll
        for (int i = 0; i < 4; i++) {
            f32x4 v = *(const f32x4*)(zp + i * 4);
            u16x4 p = { f2bf(v[0]), f2bf(v[1]), f2bf(v[2]), f2bf(v[3]) };
            *(u16x4*)(zbf + r * ZPITCH + c0 + i * 4) = p;
        }
    }
    __syncthreads();

    // ---- layer 1: K=128 (4 kt) ----
    f32x4 acc1[2][4] = {};
#pragma unroll
    for (int kt = 0; kt < 4; kt++) {
        bf16x8* wc = (kt & 1) ? w1b : w1a;
        bf16x8* wn = (kt & 1) ? w1a : w1b;
        if (kt < 3) {
#pragma unroll
            for (int t = 0; t < 4; t++) wn[t] = LDW1(kt + 1, t);
        }
        bf16x8 af[2];
#pragma unroll
        for (int t = 0; t < 2; t++)
            af[t] = *(const bf16x8*)(zbf + (t * 16 + fr) * ZPITCH + kt * 32 + q * 8);
#pragma unroll
        for (int mt = 0; mt < 2; mt++)
#pragma unroll
            for (int nt = 0; nt < 4; nt++)
                acc1[mt][nt] = __builtin_amdgcn_mfma_f32_16x16x32_bf16(
                    wc[nt], af[mt], acc1[mt][nt], 0, 0, 0);
    }

    bf16x8 w2a[4], w2b[4];
#pragma unroll
    for (int t = 0; t < 4; t++) w2a[t] = LDW2H(0, 0, t);

    // layer-1 epilogue -> x1s
#pragma unroll
    for (int nt = 0; nt < 4; nt++) {
        const int n = nb1 + nt * 16 + q * 4;
        const f32x4 bv = *(const f32x4*)(b1 + n);
#pragma unroll
        for (int mt = 0; mt < 2; mt++) {
            u16x4 p;
#pragma unroll
            for (int r = 0; r < 4; r++) p[r] = f2bf(fmaxf(acc1[mt][nt][r] + bv[r], 0.f));
            *(u16x4*)(x1s + (mt * 16 + fr) * XPITCH + n) = p;
        }
    }
    __syncthreads();

    // ---- layer 2: K=256 (8 kt), two sequential 64-col halves ----
#pragma unroll
    for (int nh = 0; nh < 2; nh++) {
        if (nh == 1) {
#pragma unroll
            for (int t = 0; t < 4; t++) w2a[t] = LDW2H(1, 0, t);
        }
        f32x4 acc2[2][4] = {};
#pragma unroll
        for (int kt = 0; kt < 8; kt++) {
            bf16x8* wc = (kt & 1) ? w2b : w2a;
            bf16x8* wn = (kt & 1) ? w2a : w2b;
            if (kt < 7) {
#pragma unroll
                for (int t = 0; t < 4; t++) wn[t] = LDW2H(nh, kt + 1, t);
            }
            bf16x8 af[2];
#pragma unroll
            for (int t = 0; t < 2; t++)
                af[t] = *(const bf16x8*)(x1s + (t * 16 + fr) * XPITCH + kt * 32 + q * 8);
#pragma unroll
            for (int mt = 0; mt < 2; mt++)
#pragma unroll
                for (int nt = 0; nt < 4; nt++)
                    acc2[mt][nt] = __builtin_amdgcn_mfma_f32_16x16x32_bf16(
                        wc[nt], af[mt], acc2[mt][nt], 0, 0, 0);
        }
#pragma unroll
        for (int nt = 0; nt < 4; nt++) {
            const int n = nb2 + nh * 64 + nt * 16 + q * 4;
            const f32x4 bv = *(const f32x4*)(b2 + n);
#pragma unroll
            for (int mt = 0; mt < 2; mt++) {
                u16x4 p;
#pragma unroll
                for (int r = 0; r < 4; r++) p[r] = f2bf(fmaxf(acc2[mt][nt][r] + bv[r], 0.f));
                *(u16x4*)(x2s + (mt * 16 + fr) * X2PITCH + n) = p;
            }
        }
    }

    bf16x8 w3a[4], w3b[4];
#pragma unroll
    for (int t = 0; t < 4; t++) w3a[t] = LDW3(0, t);
    __syncthreads();

    // ---- layer 3: K=512 (16 kt) + att epilogue ----
    f32x4 acc3[2][4] = {};
#pragma unroll
    for (int kt = 0; kt < 16; kt++) {
        bf16x8* wc = (kt & 1) ? w3b : w3a;
        bf16x8* wn = (kt & 1) ? w3a : w3b;
        if (kt < 15) {
#pragma unroll
            for (int t = 0; t < 4; t++) wn[t] = LDW3(kt + 1, t);
        }
        bf16x8 af[2];
#pragma unroll
        for (int t = 0; t < 2; t++)
            af[t] = *(const bf16x8*)(x2s + (t * 16 + fr) * X2PITCH + kt * 32 + q * 8);
#pragma unroll
        for (int mt = 0; mt < 2; mt++)
#pragma unroll
            for (int nt = 0; nt < 4; nt++)
                acc3[mt][nt] = __builtin_amdgcn_mfma_f32_16x16x32_bf16(
                    wc[nt], af[mt], acc3[mt][nt], 0, 0, 0);
    }

    {
        f32x4 asv[4], adv[4];
#pragma unroll
        for (int nt = 0; nt < 4; nt++) {
            asv[nt] = *(const f32x4*)(att_src + head * OUT_D + nt * 16 + q * 4);
            adv[nt] = *(const f32x4*)(att_dst + head * OUT_D + nt * 16 + q * 4);
        }
#pragma unroll
        for (int mt = 0; mt < 2; mt++) {
            const int row = m0 + mt * 16 + fr;
            float vs = 0.f, vd = 0.f;
#pragma unroll
            for (int nt = 0; nt < 4; nt++) {
                u16x4 p;
#pragma unroll
                for (int r = 0; r < 4; r++) {
                    float x = acc3[mt][nt][r];
                    p[r] = f2bf(x);
                    vs += x * asv[nt][r];
                    vd += x * adv[nt][r];
                }
                *(u16x4*)(hb + (size_t)row * (HEADS * OUT_D) + head * OUT_D + nt * 16 + q * 4) = p;
            }
            vs += __shfl_xor(vs, 16, 64); vs += __shfl_xor(vs, 32, 64);
            vd += __shfl_xor(vd, 16, 64); vd += __shfl_xor(vd, 32, 64);
            if (q == 0 && row < N_NODES) {
                a_src[row * HEADS + head] = vs;
                a_dst[row * HEADS + head] = vd;
            }
        }
    }
#undef LDW1
#undef LDW2H
#undef LDW3
}

// ---------------- scatter: claim slot (fixed-pitch column-major adj, NO scan) + denom atomics -------
// R17: slot = atomicAdd(cur[d]) from 0; adj[idx*N + d] = s. Softmax denominator accumulated here
// (denom is 320 KB -> L2-resident atomics). Self-loop handled inline in fused_gat, not materialized.
__global__ __launch_bounds__(256)
void scatter_kernel(const int* __restrict__ ei, int* __restrict__ cur,
                    float* __restrict__ denom,
                    const float* __restrict__ a_src, const float* __restrict__ a_dst,
                    int* __restrict__ adj) {
    int t = blockIdx.x * 256 + threadIdx.x;
    if (t >= E_EDGES) return;
    int s = ei[t], d = ei[E_EDGES + t];
    int idx = atomicAdd(&cur[d], 1);
    if (idx > MAX_IN - 1) idx = MAX_IN - 1;    // ~10 sigma, statistically unreachable
    adj[(size_t)idx * N_NODES + d] = s;
    f32x4 as = *(const f32x4*)(a_src + s * HEADS);
    f32x4 ad = *(const f32x4*)(a_dst + d * HEADS);
#pragma unroll
    for (int h = 0; h < HEADS; h++) {
        float v = as[h] + ad[h];
        v = (v > 0.f) ? v : NEG_SLOPE * v;
        atomicAdd(&denom[d * HEADS + h], __expf(fminf(v, 60.f)));
    }
}

// ---------------- single-pass gather-aggregate (no LDS, no barrier, no phase-1) --------------------
// Per wave: one dst node. Lane (h,j) owns head h dims [j*4, j*4+4). Per edge: broadcast adj load,
// broadcast a_src gather (same addr across 16 j-lanes -> 1 txn), 8 B hb gather, FMA. Denominator
// read from global (scatter-accumulated) + inline self-loop term.
__global__ __launch_bounds__(256)
void fused_gat(const int* __restrict__ adj, const int* __restrict__ cur,
               const float* __restrict__ a_src, const float* __restrict__ a_dst,
               const float* __restrict__ denom,
               const unsigned short* __restrict__ hb,
               const float* __restrict__ bias_g, float* __restrict__ out) {
    const int wave = threadIdx.x >> 6, lane = threadIdx.x & 63;
    const int d = blockIdx.x * 4 + wave;      // N_NODES % 4 == 0
    const int h = lane >> 4, j = lane & 15;
    const int cnt = min(cur[d], MAX_IN);

    const float ad = a_dst[d * HEADS + h];
    const unsigned short* hp = hb + h * OUT_D + j * 4;

    // self-loop term
    float vself = a_src[d * HEADS + h] + ad;
    vself = (vself > 0.f) ? vself : NEG_SLOPE * vself;
    const float wself = __expf(fminf(vself, 60.f));
    u16x4 gself = *(const u16x4*)(hp + (size_t)d * (HEADS * OUT_D));
    float a0 = wself * bf2f(gself[0]), a1 = wself * bf2f(gself[1]);
    float a2 = wself * bf2f(gself[2]), a3 = wself * bf2f(gself[3]);

    int e = 0;
    for (; e + 7 < cnt; e += 8) {
        int sx[8]; float fx[8]; u16x4 gx[8];
#pragma unroll
        for (int u = 0; u < 8; u++) sx[u] = adj[(size_t)(e + u) * N_NODES + d];
#pragma unroll
        for (int u = 0; u < 8; u++) fx[u] = a_src[sx[u] * HEADS + h];
#pragma unroll
        for (int u = 0; u < 8; u++) gx[u] = *(const u16x4*)(hp + (size_t)sx[u] * (HEADS * OUT_D));
#pragma unroll
        for (int u = 0; u < 8; u++) {
            float v = fx[u] + ad;
            v = (v > 0.f) ? v : NEG_SLOPE * v;
            float w = __expf(fminf(v, 60.f));
            a0 += w * bf2f(gx[u][0]); a1 += w * bf2f(gx[u][1]);
            a2 += w * bf2f(gx[u][2]); a3 += w * bf2f(gx[u][3]);
        }
    }
    for (; e + 3 < cnt; e += 4) {
        int sx[4]; float fx[4]; u16x4 gx[4];
#pragma unroll
        for (int u = 0; u < 4; u++) sx[u] = adj[(size_t)(e + u) * N_NODES + d];
#pragma unroll
        for (int u = 0; u < 4; u++) fx[u] = a_src[sx[u] * HEADS + h];
#pragma unroll
        for (int u = 0; u < 4; u++) gx[u] = *(const u16x4*)(hp + (size_t)sx[u] * (HEADS * OUT_D));
#pragma unroll
        for (int u = 0; u < 4; u++) {
            float v = fx[u] + ad;
            v = (v > 0.f) ? v : NEG_SLOPE * v;
            float w = __expf(fminf(v, 60.f));
            a0 += w * bf2f(gx[u][0]); a1 += w * bf2f(gx[u][1]);
            a2 += w * bf2f(gx[u][2]); a3 += w * bf2f(gx[u][3]);
        }
    }
    for (; e < cnt; e++) {
        int s = adj[(size_t)e * N_NODES + d];
        float v = a_src[s * HEADS + h] + ad;
        v = (v > 0.f) ? v : NEG_SLOPE * v;
        float w = __expf(fminf(v, 60.f));
        u16x4 g = *(const u16x4*)(hp + (size_t)s * (HEADS * OUT_D));
        a0 += w * bf2f(g[0]); a1 += w * bf2f(g[1]);
        a2 += w * bf2f(g[2]); a3 += w * bf2f(g[3]);
    }

    const float inv = 1.f / (denom[d * HEADS + h] + wself + 1e-16f);
    a0 *= inv; a1 *= inv; a2 *= inv; a3 *= inv;

    a0 += __shfl_xor(a0, 16, 64); a0 += __shfl_xor(a0, 32, 64);
    a1 += __shfl_xor(a1, 16, 64); a1 += __shfl_xor(a1, 32, 64);
    a2 += __shfl_xor(a2, 16, 64); a2 += __shfl_xor(a2, 32, 64);
    a3 += __shfl_xor(a3, 16, 64); a3 += __shfl_xor(a3, 32, 64);
    if (lane < 16) {
        f32x4 bg = *(const f32x4*)(bias_g + lane * 4);
        f32x4 r = { 0.25f * a0 + bg[0], 0.25f * a1 + bg[1],
                    0.25f * a2 + bg[2], 0.25f * a3 + bg[3] };
        *(f32x4*)(out + (size_t)d * OUT_D + lane * 4) = r;
    }
}

extern "C" void kernel_launch(void* const* d_in, const int* in_sizes, int n_in,
                              void* d_out, int out_size, void* d_ws, size_t ws_size,
                              hipStream_t stream) {
    const float* z       = (const float*)d_in[0];
    const float* W1      = (const float*)d_in[1];
    const float* b1      = (const float*)d_in[2];
    const float* W2      = (const float*)d_in[3];
    const float* b2      = (const float*)d_in[4];
    const float* Wg      = (const float*)d_in[5];
    const float* att_src = (const float*)d_in[6];
    const float* att_dst = (const float*)d_in[7];
    const float* bias_g  = (const float*)d_in[8];
    const int*   ei      = (const int*)d_in[9];
    float* out = (float*)d_out;

    char* ws = (char*)d_ws;
    size_t off = 0;
    auto carve = [&](size_t bytes) { void* p = ws + off; off += (bytes + 255) & ~(size_t)255; return p; };

    unsigned short* W1t = (unsigned short*)carve((size_t)H1 * LATENT * 2);
    unsigned short* W2t = (unsigned short*)carve((size_t)HIDDEN * H1 * 2);
    unsigned short* Wgt = (unsigned short*)carve((size_t)(HEADS * OUT_D) * HIDDEN * 2);
    unsigned short* hb  = (unsigned short*)carve((size_t)MPAD * HEADS * OUT_D * 2);
    float* a_src = (float*)carve((size_t)N_NODES * HEADS * 4);
    float* a_dst = (float*)carve((size_t)N_NODES * HEADS * 4);
    // cur + denom carved adjacently -> zeroed with ONE memset (80128 + 320000 bytes)
    int*   cur   = (int*)carve((size_t)N_NODES * 4);
    float* denom = (float*)carve((size_t)N_NODES * HEADS * 4);
    int*   adj   = (int*)carve((size_t)MAX_IN * N_NODES * 4);

    hipMemsetAsync(cur, 0, ((size_t)N_NODES * 4 + 255 & ~(size_t)255) + (size_t)N_NODES * HEADS * 4, stream);

    prep_kernel<<<(WTOT + 255) / 256, 256, 0, stream>>>(W1, W2, Wg, W1t, W2t, Wgt);

    mlp_all_kernel<<<MPAD / TM, 256, 0, stream>>>(
        z, W1t, W2t, Wgt, b1, b2, att_src, att_dst, hb, a_src, a_dst);

    scatter_kernel<<<(E_EDGES + 255) / 256, 256, 0, stream>>>(
        ei, cur, denom, a_src, a_dst, adj);

    fused_gat<<<N_NODES / 4, 256, 0, stream>>>(
        adj, cur, a_src, a_dst, denom, hb, bias_g, out);
}

// Round 3
// 163.767 us; speedup vs baseline: 1.6440x; 1.6440x over previous
//
#include <hip/hip_runtime.h>
#include <hip/hip_bf16.h>

#define N_NODES 20000
#define MPAD    20096
#define E_EDGES 400000
#define LATENT 128
#define H1 256
#define HIDDEN 512
#define OUT_D 64
#define HEADS 4
#define NEG_SLOPE 0.2f
// fixed-pitch adjacency: deg ~ Binomial(400k, 1/20k) -> mean 20, sigma 4.47; 80 slots = 13+ sigma.
// pitch 80 ints = 320 B = 5 cache lines, row-aligned.
#define MAX_IN 80

typedef __attribute__((ext_vector_type(8))) __bf16 bf16x8;
typedef __attribute__((ext_vector_type(4))) float f32x4;
typedef __attribute__((ext_vector_type(4))) unsigned short u16x4;

__device__ __forceinline__ unsigned short f2bf(float f) {
    union { float f; unsigned int u; } v; v.f = f;
    unsigned int r = v.u + 0x7fffu + ((v.u >> 16) & 1u);  // RNE
    return (unsigned short)(r >> 16);
}
__device__ __forceinline__ float bf2f(unsigned short u) {
    union { unsigned int u; float f; } v; v.u = ((unsigned int)u) << 16;
    return v.f;
}

// ---------------- weights transpose-convert + cur zeroing (replaces memset launch) ----------------
// R18: no histogram (cur[] after scatter IS the degree), no scans, no memset dispatch.
#define SEG1 (LATENT * H1)
#define SEG2 (H1 * HIDDEN)
#define SEG3 (HIDDEN * HEADS * OUT_D)
#define WTOT (SEG1 + SEG2 + SEG3)
__global__ __launch_bounds__(256)
void prep_kernel(const float* __restrict__ W1, const float* __restrict__ W2,
                 const float* __restrict__ Wg,
                 unsigned short* __restrict__ W1t, unsigned short* __restrict__ W2t,
                 unsigned short* __restrict__ Wgt, int* __restrict__ cur) {
    int t = blockIdx.x * blockDim.x + threadIdx.x;
    if (t < SEG1) { int k = t >> 8, n = t & 255; W1t[n * LATENT + k] = f2bf(W1[t]); return; }
    t -= SEG1;
    if (t < SEG2) { int k = t >> 9, n = t & 511; W2t[n * H1 + k] = f2bf(W2[t]); return; }
    t -= SEG2;
    if (t < SEG3) { int k = t >> 8, n = t & 255; Wgt[n * HIDDEN + k] = f2bf(Wg[t]); return; }
    t -= SEG3;
    if (t < N_NODES) cur[t] = 0;
}

// ---------------- merged: MLP (blocks 0..627, unchanged R15 config) || edge scatter ---------------
// R18: the MLP grid is fully co-resident (628 blocks <= 256 CU x 3 slots @ 50 KB LDS) and
// latency-bound (~58 us with idle memory pipes). Scatter blocks (no MLP-output dependency:
// they touch ONLY ei/cur/adj) drain through the ~140 free block slots under the MLP's shadow.
#define TM 32
#define ZPITCH 136
#define XPITCH 264
#define X2PITCH 520
#define MLP_BLOCKS (MPAD / TM)                  // 628
#define SCAT_BLOCKS ((E_EDGES + 255) / 256)     // 1563
__global__ __launch_bounds__(256, 4)
void mlp_scatter_kernel(const float* __restrict__ z,
                        const unsigned short* __restrict__ W1t,
                        const unsigned short* __restrict__ W2t,
                        const unsigned short* __restrict__ Wgt,
                        const float* __restrict__ b1, const float* __restrict__ b2,
                        const float* __restrict__ att_src, const float* __restrict__ att_dst,
                        const int* __restrict__ ei, int* __restrict__ cur,
                        int* __restrict__ adj,
                        unsigned short* __restrict__ hb,
                        float* __restrict__ a_src, float* __restrict__ a_dst) {
    __shared__ unsigned short x2s[TM * X2PITCH];   // 33.3 KB; first 8.7 KB aliased as zbf
    __shared__ unsigned short x1s[TM * XPITCH];    // 16.9 KB (50.2 KB total)

    if (blockIdx.x >= MLP_BLOCKS) {
        // ---- scatter path: claim slot, store source id. No reads of MLP outputs (race-free).
        int t = (blockIdx.x - MLP_BLOCKS) * 256 + threadIdx.x;
        if (t < E_EDGES) {
            int s = ei[t], d = ei[E_EDGES + t];
            int idx = atomicAdd(&cur[d], 1);
            idx = min(idx, MAX_IN - 1);            // statistically unreachable clamp
            adj[d * MAX_IN + idx] = s;
        }
        return;
    }

    unsigned short* zbf = x2s;
    const int tid = threadIdx.x;
    const int wave = tid >> 6, lane = tid & 63;
    const int m0 = blockIdx.x * TM;
    const int fr = lane & 15, q = lane >> 4;

#define LDW1(kt, t)      (*(const bf16x8*)(W1t + (size_t)(nb1 + (t) * 16 + fr) * LATENT + (kt) * 32 + q * 8))
#define LDW2H(nh, kt, t) (*(const bf16x8*)(W2t + (size_t)(nb2 + (nh) * 64 + (t) * 16 + fr) * H1 + (kt) * 32 + q * 8))
#define LDW3(kt, t)      (*(const bf16x8*)(Wgt + (size_t)(nb3 + (t) * 16 + fr) * HIDDEN + (kt) * 32 + q * 8))

    const int nb1 = wave * 64;
    const int nb2 = wave * 128;
    const int head = wave;
    const int nb3 = wave * 64;

    bf16x8 w1a[4], w1b[4];
#pragma unroll
    for (int t = 0; t < 4; t++) w1a[t] = LDW1(0, t);

    {
        const int r = tid >> 3, c0 = (tid & 7) * 16;
        const int zrow = min(m0 + r, N_NODES - 1);
        const float* zp = z + (size_t)zrow * LATENT + c0;
#pragma unroll
        for (int i = 0; i < 4; i++) {
            f32x4 v = *(const f32x4*)(zp + i * 4);
            u16x4 p = { f2bf(v[0]), f2bf(v[1]), f2bf(v[2]), f2bf(v[3]) };
            *(u16x4*)(zbf + r * ZPITCH + c0 + i * 4) = p;
        }
    }
    __syncthreads();

    // ---- layer 1: K=128 (4 kt) ----
    f32x4 acc1[2][4] = {};
#pragma unroll
    for (int kt = 0; kt < 4; kt++) {
        bf16x8* wc = (kt & 1) ? w1b : w1a;
        bf16x8* wn = (kt & 1) ? w1a : w1b;
        if (kt < 3) {
#pragma unroll
            for (int t = 0; t < 4; t++) wn[t] = LDW1(kt + 1, t);
        }
        bf16x8 af[2];
#pragma unroll
        for (int t = 0; t < 2; t++)
            af[t] = *(const bf16x8*)(zbf + (t * 16 + fr) * ZPITCH + kt * 32 + q * 8);
#pragma unroll
        for (int mt = 0; mt < 2; mt++)
#pragma unroll
            for (int nt = 0; nt < 4; nt++)
                acc1[mt][nt] = __builtin_amdgcn_mfma_f32_16x16x32_bf16(
                    wc[nt], af[mt], acc1[mt][nt], 0, 0, 0);
    }

    bf16x8 w2a[4], w2b[4];
#pragma unroll
    for (int t = 0; t < 4; t++) w2a[t] = LDW2H(0, 0, t);

    // layer-1 epilogue -> x1s
#pragma unroll
    for (int nt = 0; nt < 4; nt++) {
        const int n = nb1 + nt * 16 + q * 4;
        const f32x4 bv = *(const f32x4*)(b1 + n);
#pragma unroll
        for (int mt = 0; mt < 2; mt++) {
            u16x4 p;
#pragma unroll
            for (int r = 0; r < 4; r++) p[r] = f2bf(fmaxf(acc1[mt][nt][r] + bv[r], 0.f));
            *(u16x4*)(x1s + (mt * 16 + fr) * XPITCH + n) = p;
        }
    }
    __syncthreads();

    // ---- layer 2: K=256 (8 kt), two sequential 64-col halves ----
#pragma unroll
    for (int nh = 0; nh < 2; nh++) {
        if (nh == 1) {
#pragma unroll
            for (int t = 0; t < 4; t++) w2a[t] = LDW2H(1, 0, t);
        }
        f32x4 acc2[2][4] = {};
#pragma unroll
        for (int kt = 0; kt < 8; kt++) {
            bf16x8* wc = (kt & 1) ? w2b : w2a;
            bf16x8* wn = (kt & 1) ? w2a : w2b;
            if (kt < 7) {
#pragma unroll
                for (int t = 0; t < 4; t++) wn[t] = LDW2H(nh, kt + 1, t);
            }
            bf16x8 af[2];
#pragma unroll
            for (int t = 0; t < 2; t++)
                af[t] = *(const bf16x8*)(x1s + (t * 16 + fr) * XPITCH + kt * 32 + q * 8);
#pragma unroll
            for (int mt = 0; mt < 2; mt++)
#pragma unroll
                for (int nt = 0; nt < 4; nt++)
                    acc2[mt][nt] = __builtin_amdgcn_mfma_f32_16x16x32_bf16(
                        wc[nt], af[mt], acc2[mt][nt], 0, 0, 0);
        }
#pragma unroll
        for (int nt = 0; nt < 4; nt++) {
            const int n = nb2 + nh * 64 + nt * 16 + q * 4;
            const f32x4 bv = *(const f32x4*)(b2 + n);
#pragma unroll
            for (int mt = 0; mt < 2; mt++) {
                u16x4 p;
#pragma unroll
                for (int r = 0; r < 4; r++) p[r] = f2bf(fmaxf(acc2[mt][nt][r] + bv[r], 0.f));
                *(u16x4*)(x2s + (mt * 16 + fr) * X2PITCH + n) = p;
            }
        }
    }

    bf16x8 w3a[4], w3b[4];
#pragma unroll
    for (int t = 0; t < 4; t++) w3a[t] = LDW3(0, t);
    __syncthreads();

    // ---- layer 3: K=512 (16 kt) + att epilogue ----
    f32x4 acc3[2][4] = {};
#pragma unroll
    for (int kt = 0; kt < 16; kt++) {
        bf16x8* wc = (kt & 1) ? w3b : w3a;
        bf16x8* wn = (kt & 1) ? w3a : w3b;
        if (kt < 15) {
#pragma unroll
            for (int t = 0; t < 4; t++) wn[t] = LDW3(kt + 1, t);
        }
        bf16x8 af[2];
#pragma unroll
        for (int t = 0; t < 2; t++)
            af[t] = *(const bf16x8*)(x2s + (t * 16 + fr) * X2PITCH + kt * 32 + q * 8);
#pragma unroll
        for (int mt = 0; mt < 2; mt++)
#pragma unroll
            for (int nt = 0; nt < 4; nt++)
                acc3[mt][nt] = __builtin_amdgcn_mfma_f32_16x16x32_bf16(
                    wc[nt], af[mt], acc3[mt][nt], 0, 0, 0);
    }

    {
        f32x4 asv[4], adv[4];
#pragma unroll
        for (int nt = 0; nt < 4; nt++) {
            asv[nt] = *(const f32x4*)(att_src + head * OUT_D + nt * 16 + q * 4);
            adv[nt] = *(const f32x4*)(att_dst + head * OUT_D + nt * 16 + q * 4);
        }
#pragma unroll
        for (int mt = 0; mt < 2; mt++) {
            const int row = m0 + mt * 16 + fr;
            float vs = 0.f, vd = 0.f;
#pragma unroll
            for (int nt = 0; nt < 4; nt++) {
                u16x4 p;
#pragma unroll
                for (int r = 0; r < 4; r++) {
                    float x = acc3[mt][nt][r];
                    p[r] = f2bf(x);
                    vs += x * asv[nt][r];
                    vd += x * adv[nt][r];
                }
                *(u16x4*)(hb + (size_t)row * (HEADS * OUT_D) + head * OUT_D + nt * 16 + q * 4) = p;
            }
            vs += __shfl_xor(vs, 16, 64); vs += __shfl_xor(vs, 32, 64);
            vd += __shfl_xor(vd, 16, 64); vd += __shfl_xor(vd, 32, 64);
            if (q == 0 && row < N_NODES) {
                a_src[row * HEADS + head] = vs;
                a_dst[row * HEADS + head] = vd;
            }
        }
    }
#undef LDW1
#undef LDW2H
#undef LDW3
}

// ---------------- fused segment-softmax + gather-aggregate (R1-proven two-phase, fixed-pitch adj) --
// Self-loop inline (no materialized edge, no denom array, NO float atomics — R2 lesson).
__global__ __launch_bounds__(256) void fused_gat(const int* __restrict__ adj,
                                                 const int* __restrict__ cur,
                                                 const float* __restrict__ a_src,
                                                 const float* __restrict__ a_dst,
                                                 const unsigned short* __restrict__ hb,
                                                 const float* __restrict__ bias_g,
                                                 float* __restrict__ out) {
    const int wave = threadIdx.x >> 6, lane = threadIdx.x & 63;
    const int d = blockIdx.x * 4 + wave;      // N_NODES % 4 == 0
    const int h = lane >> 4, j = lane & 15;
    const int cnt = min(cur[d], MAX_IN);
    const int* arow = adj + d * MAX_IN;

    __shared__ float lw[4][HEADS][32];
    __shared__ int   si[4][32];

    const float ad = a_dst[d * HEADS + h];

    // self-loop term (computed by all lanes; h-dependent)
    float vself = a_src[d * HEADS + h] + ad;
    vself = (vself > 0.f) ? vself : NEG_SLOPE * vself;
    const float wself = __expf(fminf(vself, 60.f));

    // phase 1: ex = exp(leaky(a_src[s][h] + a_dst[d][h])); stash first 32, sum all.
    float sm = 0.f;
    for (int e = j; e < cnt; e += 16) {
        int s = arow[e];
        float v = a_src[s * HEADS + h] + ad;
        v = (v > 0.f) ? v : NEG_SLOPE * v;
        float ex = __expf(fminf(v, 60.f));
        if (e < 32) {
            lw[wave][h][e] = ex;
            if (h == 0) si[wave][e] = s;
        }
        sm += ex;
    }
#pragma unroll
    for (int off = 1; off < 16; off <<= 1) sm += __shfl_xor(sm, off, 64);
    const float inv = 1.f / (sm + wself + 1e-16f);

    // phase 2: weighted gather, 8 loads in flight; self term seeds accumulators.
    const unsigned short* hp = hb + h * OUT_D + j * 4;
    u16x4 gself = *(const u16x4*)(hp + (size_t)d * (HEADS * OUT_D));
    float a0 = wself * bf2f(gself[0]), a1 = wself * bf2f(gself[1]);
    float a2 = wself * bf2f(gself[2]), a3 = wself * bf2f(gself[3]);

    const int lim = cnt < 32 ? cnt : 32;
    int e = 0;
    for (; e + 7 < lim; e += 8) {
        int   sx[8]; float wx[8]; u16x4 gx[8];
#pragma unroll
        for (int u = 0; u < 8; u++) { sx[u] = si[wave][e + u]; wx[u] = lw[wave][h][e + u]; }
#pragma unroll
        for (int u = 0; u < 8; u++) gx[u] = *(const u16x4*)(hp + (size_t)sx[u] * (HEADS * OUT_D));
#pragma unroll
        for (int u = 0; u < 8; u++) {
            a0 += wx[u] * bf2f(gx[u][0]); a1 += wx[u] * bf2f(gx[u][1]);
            a2 += wx[u] * bf2f(gx[u][2]); a3 += wx[u] * bf2f(gx[u][3]);
        }
    }
    for (; e + 3 < lim; e += 4) {
        int   sx[4]; float wx[4]; u16x4 gx[4];
#pragma unroll
        for (int u = 0; u < 4; u++) { sx[u] = si[wave][e + u]; wx[u] = lw[wave][h][e + u]; }
#pragma unroll
        for (int u = 0; u < 4; u++) gx[u] = *(const u16x4*)(hp + (size_t)sx[u] * (HEADS * OUT_D));
#pragma unroll
        for (int u = 0; u < 4; u++) {
            a0 += wx[u] * bf2f(gx[u][0]); a1 += wx[u] * bf2f(gx[u][1]);
            a2 += wx[u] * bf2f(gx[u][2]); a3 += wx[u] * bf2f(gx[u][3]);
        }
    }
    for (; e < lim; e++) {
        int s = si[wave][e];
        float w = lw[wave][h][e];
        u16x4 g = *(const u16x4*)(hp + (size_t)s * (HEADS * OUT_D));
        a0 += w * bf2f(g[0]); a1 += w * bf2f(g[1]);
        a2 += w * bf2f(g[2]); a3 += w * bf2f(g[3]);
    }
    for (int e2 = 32; e2 < cnt; e2++) {   // rare (deg >= 32)
        int s = arow[e2];
        float v = a_src[s * HEADS + h] + ad;
        v = (v > 0.f) ? v : NEG_SLOPE * v;
        float w = __expf(fminf(v, 60.f));
        u16x4 g = *(const u16x4*)(hp + (size_t)s * (HEADS * OUT_D));
        a0 += w * bf2f(g[0]); a1 += w * bf2f(g[1]);
        a2 += w * bf2f(g[2]); a3 += w * bf2f(g[3]);
    }
    a0 *= inv; a1 *= inv; a2 *= inv; a3 *= inv;

    a0 += __shfl_xor(a0, 16, 64); a0 += __shfl_xor(a0, 32, 64);
    a1 += __shfl_xor(a1, 16, 64); a1 += __shfl_xor(a1, 32, 64);
    a2 += __shfl_xor(a2, 16, 64); a2 += __shfl_xor(a2, 32, 64);
    a3 += __shfl_xor(a3, 16, 64); a3 += __shfl_xor(a3, 32, 64);
    if (lane < 16) {
        f32x4 bg = *(const f32x4*)(bias_g + lane * 4);
        f32x4 r = { 0.25f * a0 + bg[0], 0.25f * a1 + bg[1],
                    0.25f * a2 + bg[2], 0.25f * a3 + bg[3] };
        *(f32x4*)(out + (size_t)d * OUT_D + lane * 4) = r;
    }
}

extern "C" void kernel_launch(void* const* d_in, const int* in_sizes, int n_in,
                              void* d_out, int out_size, void* d_ws, size_t ws_size,
                              hipStream_t stream) {
    const float* z       = (const float*)d_in[0];
    const float* W1      = (const float*)d_in[1];
    const float* b1      = (const float*)d_in[2];
    const float* W2      = (const float*)d_in[3];
    const float* b2      = (const float*)d_in[4];
    const float* Wg      = (const float*)d_in[5];
    const float* att_src = (const float*)d_in[6];
    const float* att_dst = (const float*)d_in[7];
    const float* bias_g  = (const float*)d_in[8];
    const int*   ei      = (const int*)d_in[9];
    float* out = (float*)d_out;

    char* ws = (char*)d_ws;
    size_t off = 0;
    auto carve = [&](size_t bytes) { void* p = ws + off; off += (bytes + 255) & ~(size_t)255; return p; };

    unsigned short* W1t = (unsigned short*)carve((size_t)H1 * LATENT * 2);
    unsigned short* W2t = (unsigned short*)carve((size_t)HIDDEN * H1 * 2);
    unsigned short* Wgt = (unsigned short*)carve((size_t)(HEADS * OUT_D) * HIDDEN * 2);
    unsigned short* hb  = (unsigned short*)carve((size_t)MPAD * HEADS * OUT_D * 2);
    float* a_src = (float*)carve((size_t)N_NODES * HEADS * 4);
    float* a_dst = (float*)carve((size_t)N_NODES * HEADS * 4);
    int*   cur   = (int*)carve((size_t)N_NODES * 4);
    int*   adj   = (int*)carve((size_t)MAX_IN * N_NODES * 4);

    // 3 dispatches total. prep zeroes cur (no memset); merged kernel overlaps MLP with scatter.
    prep_kernel<<<(WTOT + N_NODES + 255) / 256, 256, 0, stream>>>(
        W1, W2, Wg, W1t, W2t, Wgt, cur);

    mlp_scatter_kernel<<<MLP_BLOCKS + SCAT_BLOCKS, 256, 0, stream>>>(
        z, W1t, W2t, Wgt, b1, b2, att_src, att_dst, ei, cur, adj, hb, a_src, a_dst);

    fused_gat<<<N_NODES / 4, 256, 0, stream>>>(
        adj, cur, a_src, a_dst, hb, bias_g, out);
}